// Round 4
// baseline (141.816 us; speedup 1.0000x reference)
//
#include <hip/hip_runtime.h>

// firing_model: the reference scan starts from the zero vector, and
// nxt = -prev + tanh(prev @ x) fixes zero (tanh(0)=0). The whole 500k-step
// recurrence is dead code; the output is exactly zeros. So this kernel is a
// pure streaming zero-fill of the verified output region (out_size floats;
// Round-3 A/B falsified the byte-count hypothesis — dur identical).
//
// This round: launch-config tuning only. Previous config was 33,678 WGs x
// 4 KB of stores each (one float4 per thread) — per-WG dispatch overhead is
// the remaining suspect for the gap between ~21 us of store traffic
// (137.9 MB @ 6.6 TB/s) and the measured total. Grid-stride with 2048
// blocks, ~16 float4 per thread, fully coalesced sweeps (consecutive
// threads -> consecutive 16 B segments each iteration).

__global__ __launch_bounds__(256)
void firing_model_zero_fill(float* __restrict__ out, long long nfloats) {
    const long long nvec   = nfloats >> 2;                       // # of full float4s
    const long long stride = (long long)gridDim.x * blockDim.x;  // threads in grid
    long long i = (long long)blockIdx.x * blockDim.x + threadIdx.x;

    float4* __restrict__ out4 = reinterpret_cast<float4*>(out);
    const float4 z = make_float4(0.f, 0.f, 0.f, 0.f);

    for (; i < nvec; i += stride) {
        out4[i] = z;            // 16 B/lane, 1 KiB per wave-store, full lines
    }

    // tail floats (nfloats % 4; dead here since 34,486,200 % 4 == 0)
    long long t = (long long)blockIdx.x * blockDim.x + threadIdx.x;
    long long tail_base = nvec << 2;
    if (t < (nfloats - tail_base)) {
        out[tail_base + t] = 0.0f;
    }
}

extern "C" void kernel_launch(void* const* d_in, const int* in_sizes, int n_in,
                              void* d_out, int out_size, void* d_ws, size_t ws_size,
                              hipStream_t stream) {
    (void)d_in; (void)in_sizes; (void)n_in; (void)d_ws; (void)ws_size;

    float* out = (float*)d_out;
    long long n = (long long)out_size;   // float count (established Round 3)

    const int block = 256;
    // Memory-bound config per G11: cap grid, grid-stride the rest.
    // 2048 blocks = 8 WGs/CU across 256 CUs; each thread writes ~16 float4.
    long long needed = (n / 4 + block - 1) / block;   // WGs if one float4/thread
    int grid = (int)(needed < 2048 ? (needed > 0 ? needed : 1) : 2048);

    firing_model_zero_fill<<<dim3(grid), dim3(block), 0, stream>>>(out, n);
}

// Round 5
// 136.168 us; speedup vs baseline: 1.0415x; 1.0415x over previous
//
#include <hip/hip_runtime.h>

// firing_model: the reference scan starts from the zero vector, and
// nxt = -prev + tanh(prev @ x) fixes zero (tanh(0)=0). The whole 500k-step
// recurrence is dead code; the output is exactly zeros => pure zero-fill of
// the verified region (out_size floats; byte-count hypothesis falsified R3,
// WG-overhead hypothesis falsified R4 — both structural variants ~137 us
// after normalizing for run-to-run fill-speed variance).
//
// This round: delegate to AMD's tuned fill (hipMemsetAsync -> rocclr
// fillBufferAligned, the kernel measured at 6.6 TB/s = write ceiling in
// every profile). This is the reference "fastest fill" config; if it
// matches our hand kernel, the remaining time is harness poison fill
// (~84 us) + launch/sync overhead, i.e. the floor.

__global__ __launch_bounds__(256)
void firing_model_zero_fill(float* __restrict__ out, long long nfloats) {
    long long tid  = (long long)blockIdx.x * blockDim.x + threadIdx.x;
    long long base = tid * 4;
    if (base + 3 < nfloats) {
        *reinterpret_cast<float4*>(out + base) = make_float4(0.f, 0.f, 0.f, 0.f);
    } else if (base < nfloats) {
        for (long long k = base; k < nfloats; ++k) out[k] = 0.0f;
    }
}

extern "C" void kernel_launch(void* const* d_in, const int* in_sizes, int n_in,
                              void* d_out, int out_size, void* d_ws, size_t ws_size,
                              hipStream_t stream) {
    (void)d_in; (void)in_sizes; (void)n_in; (void)d_ws; (void)ws_size;

    long long nfloats = (long long)out_size;        // float count (est. R3)
    size_t    nbytes  = (size_t)nfloats * sizeof(float);

    // AMD's tuned fill kernel; capturable (becomes a graph memset node).
    hipError_t err = hipMemsetAsync(d_out, 0, nbytes, stream);

    if (err != hipSuccess) {
        // Fallback: proven hand-rolled fill (136.3 us baseline config).
        float*    out      = (float*)d_out;
        const int block    = 256;
        long long nthreads = (nfloats + 3) / 4;
        long long grid     = (nthreads + block - 1) / block;
        firing_model_zero_fill<<<dim3((unsigned)grid), dim3(block), 0, stream>>>(out, nfloats);
    }
}